// Round 4
// baseline (4285.809 us; speedup 1.0000x reference)
//
#include <hip/hip_runtime.h>

// ---------------------------------------------------------------------------
// LSTM: B=64, SEQ=512, I=1024, H=1024, O=512, fp32 in/out.
// Row space: n' = hid*4 + gate (gate-interleaved) so MFMA C-layout puts all
// 4 gate preacts of one (hid,batch) in ONE lane (acc[rr] = gate rr).
//   prep:   pack Wh4/Wx4 -> bf16 [n'=4096][1024], bias[n'], X->bf16,
//           h0 bf16 buffer + poison bufs 1..3, wT for output GEMM
//   phase1: Xg[t][jb][n'][b16] = X . Wx^T + bias (bf16 MFMA, m97 staging)
//   phase2: persistent recurrence, 128 blocks x 512 thr.
//           R10 = R9 minus ALL block barriers: wave-autonomous exchange.
//           R9 evidence: step 6400cy, MFMA 525cy + VALU 650cy -> ~5100cy
//           wait (store commit -> poll detect -> 32KB stage -> 2 barriers).
//           Now: B-frag ks depends only on producer block ibb=ks, so wave w
//           polls+stages only frags 4w..4w+3 (same 8 u64/thread poll volume)
//           into double-buffered LDS and publishes an LDS epoch flag;
//           compute waves spin on the 8 LDS flags (~30cy) per chunk instead
//           of 2 __syncthreads. h repacked via 3 shuffles, each wave stores
//           its own 16 u64s. Zero barriers in the 512-step loop.
//           Safety (proofs route through LDS flags): passing all 8 flags at
//           step t => all block waves' polls (covering ALL 32 producer
//           blocks) saw h(t) => all group waves stored h(t) => finished step
//           t-1 => (a) poison buf[(t-1)&3] after compute loop is WAR-safe,
//           (b) hTl parity overwrite at t+2 safe. Poison issued after the
//           h(t+1) store; drained by vmcnt(0) before h(t+2) store => visible
//           before any poll of that buffer at t+3. MFMA chain order kept
//           (even ks -> acc0, odd -> acc1): bit-identical results.
//   out:    out[b][o] = h[b,:] . w[o,:]
// ---------------------------------------------------------------------------

typedef short short8 __attribute__((ext_vector_type(8)));   // 8 bf16
typedef float f32x4 __attribute__((ext_vector_type(4)));

typedef __attribute__((address_space(1))) const unsigned int glb_u32;
typedef __attribute__((address_space(3))) unsigned int lds_u32;

#define SEQL  512
#define POISON 0xFFFFFFFFFFFFFFFFull
#define BUFU64 16384     // u64 words per h buffer: 64 rows x 256 u64

__device__ __forceinline__ unsigned short f2bf(float f) {
    unsigned int u = __builtin_bit_cast(unsigned int, f);
    u += 0x7FFFu + ((u >> 16) & 1u);            // round-to-nearest-even
    return (unsigned short)(u >> 16);
}
__device__ __forceinline__ float bf2f(unsigned short s) {
    unsigned int u = ((unsigned int)s) << 16;
    return __builtin_bit_cast(float, u);
}
__device__ __forceinline__ float sigmoidf_fast(float x) {
    return 1.f / (1.f + __expf(-x));
}
__device__ __forceinline__ float tanhf_fast(float x) {
    return 1.f - 2.f / (1.f + __expf(2.f * x));
}
__device__ __forceinline__ void gld_lds16(const unsigned short* g, unsigned short* l) {
    __builtin_amdgcn_global_load_lds((glb_u32*)g, (lds_u32*)l, 16, 0, 0);
}

// --- prep: pack 4 gate weight mats (fp32 [1024][1024]) into bf16 [n'][1024]
__global__ void k_pack_w(const float* __restrict__ w0, const float* __restrict__ w1,
                         const float* __restrict__ w2, const float* __restrict__ w3,
                         unsigned short* __restrict__ dst) {
    int idx4 = blockIdx.x * blockDim.x + threadIdx.x;   // over 4096*256
    int np = idx4 >> 8;            // n' 0..4095
    int k4 = (idx4 & 255) * 4;
    int g = np & 3, r = np >> 2;
    const float* src = (g == 0) ? w0 : (g == 1) ? w1 : (g == 2) ? w2 : w3;
    float4 v = *(const float4*)(src + r * 1024 + k4);
    ushort4 o;
    o.x = f2bf(v.x); o.y = f2bf(v.y); o.z = f2bf(v.z); o.w = f2bf(v.w);
    *(ushort4*)(dst + (size_t)np * 1024 + k4) = o;
}

// --- prep: bias[n'], h0 bf16 buf0, poison bufs 1..3, wT (fp32 [1024][512])
__global__ void k_misc(const float* __restrict__ b_hi, const float* __restrict__ b_xi,
                       const float* __restrict__ b_hf, const float* __restrict__ b_xf,
                       const float* __restrict__ b_ho, const float* __restrict__ b_xo,
                       const float* __restrict__ b_hg, const float* __restrict__ b_xg,
                       const float* __restrict__ h0, const float* __restrict__ w,
                       float* __restrict__ bias, unsigned short* __restrict__ hbuf,
                       float* __restrict__ wT) {
    int idx = blockIdx.x * blockDim.x + threadIdx.x;
    if (idx < 4096) {
        int g = idx & 3, r = idx >> 2;                  // n'-order bias
        const float* bh = (g == 0) ? b_hi : (g == 1) ? b_hf : (g == 2) ? b_ho : b_hg;
        const float* bx = (g == 0) ? b_xi : (g == 1) ? b_xf : (g == 2) ? b_xo : b_xg;
        bias[idx] = bh[r] + bx[r];
    } else if (idx < 4096 + 65536) {
        int e = idx - 4096;                             // buf0: [b][hid] = h0
        int k = e & 1023;
        hbuf[e] = f2bf(h0[k]);
    } else if (idx < 4096 + 65536 + 524288) {
        int e = idx - 69632;
        int k = e >> 9, o = e & 511;
        wT[e] = w[o * 1024 + k];
    } else if (idx < 4096 + 65536 + 524288 + 3 * BUFU64) {
        int e = idx - (4096 + 65536 + 524288);          // poison bufs 1..3
        ((unsigned long long*)hbuf)[BUFU64 + e] = POISON;
    }
}

// --- prep: X fp32 -> bf16
__global__ void k_convert_x(const float* __restrict__ X, unsigned short* __restrict__ Xb) {
    int idx = blockIdx.x * blockDim.x + threadIdx.x;
    float4 v = ((const float4*)X)[idx];
    ushort4 o;
    o.x = f2bf(v.x); o.y = f2bf(v.y); o.z = f2bf(v.z); o.w = f2bf(v.w);
    ((ushort4*)Xb)[idx] = o;
}

// --- phase 1: Xg[t][jb][n'][b16], 128x128 tiles, m97 staging.
__global__ __launch_bounds__(256) void k_xgemm(const unsigned short* __restrict__ Wx,
                                               const unsigned short* __restrict__ Xb,
                                               const float* __restrict__ bias,
                                               unsigned short* __restrict__ Xg) {
    const int jt = blockIdx.x;          // col tile: t0=jt*2, 64 batches x 2 t
    const int n0 = blockIdx.y * 128;
    const int t0 = jt * 2;
    __shared__ unsigned short At[128 * 32];   // no pad: global_load_lds order
    __shared__ unsigned short Bt[128 * 32];
    const int tid = threadIdx.x;
    const int w   = tid >> 6;
    const int l   = tid & 63;
    const int l15 = l & 15, lq = l >> 4;
    const int wm  = w & 1, wn = w >> 1;
    const int seg = l & 3, cr = w * 16 + (l >> 2);

    const unsigned short* gA0 = Wx + (size_t)(n0 + cr) * 1024 + seg * 8;
    const unsigned short* gA1 = gA0 + (size_t)64 * 1024;
    const unsigned short* gB0 = Xb + ((size_t)cr * 512 + t0) * 1024 + seg * 8;
    const unsigned short* gB1 = gB0 + 1024;
    unsigned short* lA0 = At + w * 512;
    unsigned short* lA1 = At + 2048 + w * 512;
    unsigned short* lB0 = Bt + w * 512;
    unsigned short* lB1 = Bt + 2048 + w * 512;

    f32x4 acc[4][4];
#pragma unroll
    for (int mi = 0; mi < 4; ++mi)
#pragma unroll
        for (int nj = 0; nj < 4; ++nj)
            acc[mi][nj] = f32x4{0.f, 0.f, 0.f, 0.f};

    for (int kk = 0; kk < 32; ++kk) {
        __syncthreads();
        gld_lds16(gA0, lA0);
        gld_lds16(gA1, lA1);
        gld_lds16(gB0, lB0);
        gld_lds16(gB1, lB1);
        gA0 += 32; gA1 += 32; gB0 += 32; gB1 += 32;
        __syncthreads();
        short8 af[4], bfr[4];
#pragma unroll
        for (int mi = 0; mi < 4; ++mi)
            af[mi] = *(const short8*)(At + (wm * 64 + mi * 16 + l15) * 32 + lq * 8);
#pragma unroll
        for (int nj = 0; nj < 4; ++nj)
            bfr[nj] = *(const short8*)(Bt + (wn * 64 + nj * 16 + l15) * 32 + lq * 8);
#pragma unroll
        for (int mi = 0; mi < 4; ++mi)
#pragma unroll
            for (int nj = 0; nj < 4; ++nj)
                acc[mi][nj] = __builtin_amdgcn_mfma_f32_16x16x32_bf16(af[mi], bfr[nj], acc[mi][nj], 0, 0, 0);
    }

    // epilogue: col c = wn*64 + nj*16 + l15 -> t = t0+wn, jb = nj, b16 = l15
#pragma unroll
    for (int mi = 0; mi < 4; ++mi) {
#pragma unroll
        for (int rr = 0; rr < 4; ++rr) {
            int np = n0 + wm * 64 + mi * 16 + lq * 4 + rr;
            float bs = bias[np];
#pragma unroll
            for (int nj = 0; nj < 4; ++nj) {
                size_t idx = ((((size_t)(t0 + wn)) * 4 + nj) * 4096 + np) * 16 + l15;
                Xg[idx] = f2bf(acc[mi][nj][rr] + bs);
            }
        }
    }
}

// --- phase 2: persistent recurrence (R10: wave-autonomous, 0 barriers/step).
// 128 blocks x 512 thr: jb=blk&3 (16 batches), ibb=blk>>2 (n' rows
// [ibb*128,+128) = 32 hids x 4 gates). Wave w: rows ibb*128+w*16+[0,16).
// Lane (lq,l15): acc[rr] = gate-rr preact for hid=ibb*32+w*4+lq, b=jb*16+l15.
// hbuf = 4 x bf16[64][1024] (BUFU64 u64 each); buf[t&3] holds h(t).
// Wave w stages frags ks=4w..4w+3 (producer blocks 4w..4w+3) into
// hTl[t&1], flags[t&1][w]=t+1; compute spins on the 8 LDS flags.
__global__ __launch_bounds__(512, 1) void k_rec(const unsigned short* __restrict__ Wh,
                                                const unsigned short* __restrict__ Xg,
                                                const float* __restrict__ c0,
                                                unsigned short* __restrict__ hbuf) {
    const int blk = blockIdx.x;
    const int jb  = blk & 3;
    const int ibb = blk >> 2;
    const int tid = threadIdx.x;
    const int w   = tid >> 6;
    const int l   = tid & 63;
    const int l15 = l & 15, lq = l >> 4;

    __shared__ unsigned short hTl[2][16 * 1032];  // [parity][b16][k], stride 1032
    __shared__ unsigned flags[2][8];              // [parity][chunk] epoch flags

    if (tid < 16) ((unsigned*)flags)[tid] = 0;

    // Persistent A-fragments: rows n' = ibb*128 + w*16 + l15, all K.
    // (R3 evidence: pinned frags land in AGPRs; MFMA reads AGPR A-ops free.)
    short8 afrag[32];
    {
        const unsigned short* wrow = Wh + (size_t)(ibb * 128 + w * 16 + l15) * 1024;
#pragma unroll
        for (int ks = 0; ks < 32; ++ks)
            afrag[ks] = *(const short8*)(wrow + ks * 32 + lq * 8);
#pragma unroll
        for (int ks = 0; ks < 32; ++ks)
            asm volatile("" : "+v"(afrag[ks]));
    }

    const int hid = ibb * 32 + w * 4 + lq;     // this lane's hidden unit
    float c = c0[hid];

    unsigned long long* hb64 = (unsigned long long*)hbuf;   // BUFU64 u64 / buffer

    // staging mapping: lane -> (row fr, 16B segment fseg) of the group slice
    const int fr = l & 15;                     // batch row within group
    const int fseg = l >> 4;                   // 0..3
    const size_t rbase = (size_t)(jb * 16 + fr) * 256;

    // store/poison word (lanes < 16): row jb*16+l, u64 idx ibb*8+w
    const size_t widx = (size_t)(jb * 16 + l15) * 256 + ibb * 8 + w;

    // Xg fixed part: (( (t*4+jb)*4096 + ibb*128 + w*16 + lq*4 + rr )*16 + l15
    const size_t xg_fix = ((size_t)ibb * 128 + w * 16 + lq * 4) * 16 + l15;

    float xg[4];
#pragma unroll
    for (int rr = 0; rr < 4; ++rr)
        xg[rr] = bf2f(Xg[((size_t)jb * 4096 + rr) * 16 + xg_fix]);   // t = 0

    __syncthreads();   // flags zeroed (only barrier; outside the step loop)

    for (int t = 0; t < SEQL; ++t) {
        const int pb = t & 1;

        // --- stage: poll own 4 frags from global, write LDS, publish flag ---
        {
            const unsigned long long* src = hb64 + (size_t)(t & 3) * BUFU64 + rbase;
            unsigned long long tmp[8];
#pragma unroll
            for (int j = 0; j < 4; ++j) {
                size_t u = (size_t)(w * 4 + j) * 8 + fseg * 2;
                tmp[2 * j]     = __hip_atomic_load(src + u,     __ATOMIC_RELAXED,
                                                   __HIP_MEMORY_SCOPE_AGENT);
                tmp[2 * j + 1] = __hip_atomic_load(src + u + 1, __ATOMIC_RELAXED,
                                                   __HIP_MEMORY_SCOPE_AGENT);
            }
            for (;;) {
                int miss = 0;
#pragma unroll
                for (int j = 0; j < 8; ++j)
                    if (tmp[j] == POISON) miss |= 1 << j;
                if (!miss) break;
                __builtin_amdgcn_s_sleep(1);
#pragma unroll
                for (int j = 0; j < 8; ++j)
                    if (miss & (1 << j)) {
                        size_t u = (size_t)(w * 4 + (j >> 1)) * 8 + fseg * 2 + (j & 1);
                        tmp[j] = __hip_atomic_load(src + u, __ATOMIC_RELAXED,
                                                   __HIP_MEMORY_SCOPE_AGENT);
                    }
            }
            unsigned short* dstb = &hTl[pb][fr * 1032 + fseg * 8];
#pragma unroll
            for (int j = 0; j < 4; ++j) {
                *(unsigned long long*)(dstb + (w * 4 + j) * 32)     = tmp[2 * j];
                *(unsigned long long*)(dstb + (w * 4 + j) * 32 + 4) = tmp[2 * j + 1];
            }
            if (l == 0)
                __hip_atomic_store(&flags[pb][w], (unsigned)(t + 1),
                                   __ATOMIC_RELEASE, __HIP_MEMORY_SCOPE_WORKGROUP);
        }

        // --- compute: spin on LDS flags per chunk, MFMA (order = R9's) ---
        f32x4 acc0 = {0.f, 0.f, 0.f, 0.f}, acc1 = {0.f, 0.f, 0.f, 0.f};
        {
            const unsigned short* hl = &hTl[pb][0];
#pragma unroll
            for (int cw = 0; cw < 8; ++cw) {
                while (__hip_atomic_load(&flags[pb][cw], __ATOMIC_ACQUIRE,
                                         __HIP_MEMORY_SCOPE_WORKGROUP)
                       < (unsigned)(t + 1)) { }
#pragma unroll
                for (int j = 0; j < 4; j += 2) {
                    const int ks = cw * 4 + j;
                    short8 b0 = *(const short8*)(&hl[l15 * 1032 + ks * 32 + lq * 8]);
                    short8 b1 = *(const short8*)(&hl[l15 * 1032 + (ks + 1) * 32 + lq * 8]);
                    acc0 = __builtin_amdgcn_mfma_f32_16x16x32_bf16(afrag[ks], b0, acc0, 0, 0, 0);
                    acc1 = __builtin_amdgcn_mfma_f32_16x16x32_bf16(afrag[ks + 1], b1, acc1, 0, 0, 0);
                }
            }
        }

        // --- gates (in-register), pack h via shuffles, store + poison ---
        {
            float pi = acc0[0] + acc1[0] + xg[0];
            float pf = acc0[1] + acc1[1] + xg[1];
            float po = acc0[2] + acc1[2] + xg[2];
            float pg = acc0[3] + acc1[3] + xg[3];
            float ig = sigmoidf_fast(pi);
            float fg = sigmoidf_fast(pf);
            float og = sigmoidf_fast(po);
            float gg = tanhf_fast(pg);
            c = fg * c + ig * gg;
            float hh = og * tanhf_fast(c);

            unsigned hu = (unsigned)f2bf(hh);
            unsigned v0 = __shfl((int)hu, l15);
            unsigned v1 = __shfl((int)hu, l15 + 16);
            unsigned v2 = __shfl((int)hu, l15 + 32);
            unsigned v3 = __shfl((int)hu, l15 + 48);

            // vmcnt(0): drains last step's poison (+ retired frag/Xg loads)
            // BEFORE releasing h(t+1) -> poison-visibility ordering holds.
            asm volatile("s_waitcnt vmcnt(0)" ::: "memory");
            if (l < 16) {
                unsigned long long hv = (unsigned long long)(v0 & 0xFFFFu)
                    | ((unsigned long long)(v1 & 0xFFFFu) << 16)
                    | ((unsigned long long)(v2 & 0xFFFFu) << 32)
                    | ((unsigned long long)(v3 & 0xFFFFu) << 48);
                __hip_atomic_store(hb64 + (size_t)((t + 1) & 3) * BUFU64 + widx, hv,
                                   __ATOMIC_RELAXED, __HIP_MEMORY_SCOPE_AGENT);
                __hip_atomic_store(hb64 + (size_t)((t + 3) & 3) * BUFU64 + widx, POISON,
                                   __ATOMIC_RELAXED, __HIP_MEMORY_SCOPE_AGENT);
            }
        }

        // --- Xg prefetch for t+1 (latency hides under next stage/compute) ---
        if (t < SEQL - 1) {
            size_t base = (((size_t)(t + 1) * 4 + jb) * 4096) * 16 + xg_fix;
#pragma unroll
            for (int rr = 0; rr < 4; ++rr)
                xg[rr] = bf2f(Xg[base + (size_t)rr * 16]);
        }
    }
    // t=511 stores h(512) into buf[512&3] = buf0: final h at hbuf base
}

// --- output: out[b][o] = sum_k h[b][k] * w[o][k]
__global__ __launch_bounds__(256) void k_out(const unsigned short* __restrict__ hT,
                                             const float* __restrict__ wT,
                                             float* __restrict__ out) {
    const int b = blockIdx.x;
    const int tid = threadIdx.x;
    __shared__ float hs[1024];
#pragma unroll
    for (int p = 0; p < 4; ++p)
        hs[p * 256 + tid] = bf2f(hT[b * 1024 + p * 256 + tid]);
    __syncthreads();
    float a0 = 0.f, a1 = 0.f;
    for (int k = 0; k < 1024; ++k) {
        float hv = hs[k];
        a0 = fmaf(hv, wT[k * 512 + tid], a0);
        a1 = fmaf(hv, wT[k * 512 + 256 + tid], a1);
    }
    out[b * 512 + tid] = a0;
    out[b * 512 + 256 + tid] = a1;
}

extern "C" void kernel_launch(void* const* d_in, const int* in_sizes, int n_in,
                              void* d_out, int out_size, void* d_ws, size_t ws_size,
                              hipStream_t stream) {
    const float* X    = (const float*)d_in[0];
    const float* c0   = (const float*)d_in[1];
    const float* h0   = (const float*)d_in[2];
    const float* w_hi = (const float*)d_in[3];
    const float* w_xi = (const float*)d_in[4];
    const float* b_hi = (const float*)d_in[5];
    const float* b_xi = (const float*)d_in[6];
    const float* w_hf = (const float*)d_in[7];
    const float* w_xf = (const float*)d_in[8];
    const float* b_hf = (const float*)d_in[9];
    const float* b_xf = (const float*)d_in[10];
    const float* w_ho = (const float*)d_in[11];
    const float* w_xo = (const float*)d_in[12];
    const float* b_ho = (const float*)d_in[13];
    const float* b_xo = (const float*)d_in[14];
    const float* w_hg = (const float*)d_in[15];
    const float* w_xg = (const float*)d_in[16];
    const float* b_hg = (const float*)d_in[17];
    const float* b_xg = (const float*)d_in[18];
    const float* w    = (const float*)d_in[19];

    // workspace layout (16B aligned); ~339 MiB
    char* ws = (char*)d_ws;
    size_t off = 0;
    unsigned short* Xg  = (unsigned short*)(ws + off); off += (size_t)512 * 4096 * 64 * 2;
    unsigned short* Whp = (unsigned short*)(ws + off); off += (size_t)4096 * 1024 * 2;
    unsigned short* Wxp = (unsigned short*)(ws + off); off += (size_t)4096 * 1024 * 2;
    unsigned short* Xb  = (unsigned short*)(ws + off); off += (size_t)64 * 512 * 1024 * 2;
    float*          bias= (float*)(ws + off);          off += (size_t)4096 * 4;
    float*          wT  = (float*)(ws + off);          off += (size_t)1024 * 512 * 4;
    unsigned short* hbuf= (unsigned short*)(ws + off); off += (size_t)4 * 64 * 1024 * 2;
    if (ws_size < off) return;

    k_pack_w<<<4096, 256, 0, stream>>>(w_hi, w_hf, w_ho, w_hg, Whp);
    k_pack_w<<<4096, 256, 0, stream>>>(w_xi, w_xf, w_xo, w_xg, Wxp);
    k_misc<<<(4096 + 65536 + 524288 + 3 * BUFU64 + 255) / 256, 256, 0, stream>>>(
        b_hi, b_xi, b_hf, b_xf, b_ho, b_xo, b_hg, b_xg, h0, w, bias, hbuf, wT);
    k_convert_x<<<33554432 / 4 / 256, 256, 0, stream>>>(X, Xb);

    k_xgemm<<<dim3(256, 32), 256, 0, stream>>>(Wxp, Xb, bias, Xg);

    void* args[] = {(void*)&Whp, (void*)&Xg, (void*)&c0, (void*)&hbuf};
    hipLaunchCooperativeKernel((void*)k_rec, dim3(128), dim3(512), args, 0, stream);

    k_out<<<64, 256, 0, stream>>>(hbuf, wT, (float*)d_out);
}

// Round 5
// 3231.715 us; speedup vs baseline: 1.3262x; 1.3262x over previous
//
#include <hip/hip_runtime.h>

// ---------------------------------------------------------------------------
// LSTM: B=64, SEQ=512, I=1024, H=1024, O=512, fp32 in/out.
// Row space: n' = hid*4 + gate (gate-interleaved) so MFMA C-layout puts all
// 4 gate preacts of one (hid,batch) in ONE lane (acc[rr] = gate rr).
//   prep:   pack Wh4/Wx4 -> bf16 [n'=4096][1024], bias[n'], X->bf16,
//           h0 bf16 buffer + poison bufs 1..3, wT for output GEMM
//   phase1: Xg[t][jb][n'][b16] = X . Wx^T + bias (bf16 MFMA, m97 staging)
//   phase2: persistent recurrence, 64 blocks x 512 thr.
//           R11 = R9 exchange machinery + TWO-GROUP TIME INTERLEAVE.
//           R10 post-mortem: per-wave 8B scattered stores fragmented h-line
//           commits (WRITE 4x, FETCH 1.6x, dur 2.7x) -> keep R9's store
//           shape (128 thr, 8 adjacent thr = one full 64B line, post-bar).
//           R9 evidence: FETCH 216GB =~100x logical -> poll retry storms;
//           polls must hit round one. Here each block runs groups A,B
//           sequentially per iteration: computeA -> storeA -> poll+stageB ->
//           computeB -> storeB -> poll+stageA(t+1). Every poll targets data
//           stored ~1 compute-phase + 1 exchange-phase earlier (~1500cy
//           slack) -> first-round hit; poll-B loads issue before MFMA-A so
//           latency hides under it. Same afrag serves both groups.
//           Safety (per group, R9 proofs unchanged): poll(t) success =>
//           all 32 pair-blocks stored h(t) => all consumed h(t-1) =>
//           poisoning buf[(t-1)&3] is WAR-safe. Poison at iter i drains via
//           the next store's vmcnt(0) => visible before that buffer's next
//           data store (iter i+2) and before any poll of it (iter i+2 ph9).
//           No cross-phase deadlock: ph4 needs pair-blocks' ph8(i-1);
//           ph9 needs pair-blocks' ph3(i); both reachable by induction.
//   out:    out[b][o] = h[b,:] . w[o,:]
// ---------------------------------------------------------------------------

typedef short short8 __attribute__((ext_vector_type(8)));   // 8 bf16
typedef float f32x4 __attribute__((ext_vector_type(4)));

typedef __attribute__((address_space(1))) const unsigned int glb_u32;
typedef __attribute__((address_space(3))) unsigned int lds_u32;

#define SEQL  512
#define POISON 0xFFFFFFFFFFFFFFFFull
#define BUFU64 16384     // u64 words per h buffer: 64 rows x 256 u64

__device__ __forceinline__ unsigned short f2bf(float f) {
    unsigned int u = __builtin_bit_cast(unsigned int, f);
    u += 0x7FFFu + ((u >> 16) & 1u);            // round-to-nearest-even
    return (unsigned short)(u >> 16);
}
__device__ __forceinline__ float bf2f(unsigned short s) {
    unsigned int u = ((unsigned int)s) << 16;
    return __builtin_bit_cast(float, u);
}
__device__ __forceinline__ float sigmoidf_fast(float x) {
    return 1.f / (1.f + __expf(-x));
}
__device__ __forceinline__ float tanhf_fast(float x) {
    return 1.f - 2.f / (1.f + __expf(2.f * x));
}
__device__ __forceinline__ void gld_lds16(const unsigned short* g, unsigned short* l) {
    __builtin_amdgcn_global_load_lds((glb_u32*)g, (lds_u32*)l, 16, 0, 0);
}

// --- prep: pack 4 gate weight mats (fp32 [1024][1024]) into bf16 [n'][1024]
__global__ void k_pack_w(const float* __restrict__ w0, const float* __restrict__ w1,
                         const float* __restrict__ w2, const float* __restrict__ w3,
                         unsigned short* __restrict__ dst) {
    int idx4 = blockIdx.x * blockDim.x + threadIdx.x;   // over 4096*256
    int np = idx4 >> 8;            // n' 0..4095
    int k4 = (idx4 & 255) * 4;
    int g = np & 3, r = np >> 2;
    const float* src = (g == 0) ? w0 : (g == 1) ? w1 : (g == 2) ? w2 : w3;
    float4 v = *(const float4*)(src + r * 1024 + k4);
    ushort4 o;
    o.x = f2bf(v.x); o.y = f2bf(v.y); o.z = f2bf(v.z); o.w = f2bf(v.w);
    *(ushort4*)(dst + (size_t)np * 1024 + k4) = o;
}

// --- prep: bias[n'], h0 bf16 buf0, poison bufs 1..3, wT (fp32 [1024][512])
__global__ void k_misc(const float* __restrict__ b_hi, const float* __restrict__ b_xi,
                       const float* __restrict__ b_hf, const float* __restrict__ b_xf,
                       const float* __restrict__ b_ho, const float* __restrict__ b_xo,
                       const float* __restrict__ b_hg, const float* __restrict__ b_xg,
                       const float* __restrict__ h0, const float* __restrict__ w,
                       float* __restrict__ bias, unsigned short* __restrict__ hbuf,
                       float* __restrict__ wT) {
    int idx = blockIdx.x * blockDim.x + threadIdx.x;
    if (idx < 4096) {
        int g = idx & 3, r = idx >> 2;                  // n'-order bias
        const float* bh = (g == 0) ? b_hi : (g == 1) ? b_hf : (g == 2) ? b_ho : b_hg;
        const float* bx = (g == 0) ? b_xi : (g == 1) ? b_xf : (g == 2) ? b_xo : b_xg;
        bias[idx] = bh[r] + bx[r];
    } else if (idx < 4096 + 65536) {
        int e = idx - 4096;                             // buf0: [b][hid] = h0
        int k = e & 1023;
        hbuf[e] = f2bf(h0[k]);
    } else if (idx < 4096 + 65536 + 524288) {
        int e = idx - 69632;
        int k = e >> 9, o = e & 511;
        wT[e] = w[o * 1024 + k];
    } else if (idx < 4096 + 65536 + 524288 + 3 * BUFU64) {
        int e = idx - (4096 + 65536 + 524288);          // poison bufs 1..3
        ((unsigned long long*)hbuf)[BUFU64 + e] = POISON;
    }
}

// --- prep: X fp32 -> bf16
__global__ void k_convert_x(const float* __restrict__ X, unsigned short* __restrict__ Xb) {
    int idx = blockIdx.x * blockDim.x + threadIdx.x;
    float4 v = ((const float4*)X)[idx];
    ushort4 o;
    o.x = f2bf(v.x); o.y = f2bf(v.y); o.z = f2bf(v.z); o.w = f2bf(v.w);
    ((ushort4*)Xb)[idx] = o;
}

// --- phase 1: Xg[t][jb][n'][b16], 128x128 tiles, m97 staging.
__global__ __launch_bounds__(256) void k_xgemm(const unsigned short* __restrict__ Wx,
                                               const unsigned short* __restrict__ Xb,
                                               const float* __restrict__ bias,
                                               unsigned short* __restrict__ Xg) {
    const int jt = blockIdx.x;          // col tile: t0=jt*2, 64 batches x 2 t
    const int n0 = blockIdx.y * 128;
    const int t0 = jt * 2;
    __shared__ unsigned short At[128 * 32];   // no pad: global_load_lds order
    __shared__ unsigned short Bt[128 * 32];
    const int tid = threadIdx.x;
    const int w   = tid >> 6;
    const int l   = tid & 63;
    const int l15 = l & 15, lq = l >> 4;
    const int wm  = w & 1, wn = w >> 1;
    const int seg = l & 3, cr = w * 16 + (l >> 2);

    const unsigned short* gA0 = Wx + (size_t)(n0 + cr) * 1024 + seg * 8;
    const unsigned short* gA1 = gA0 + (size_t)64 * 1024;
    const unsigned short* gB0 = Xb + ((size_t)cr * 512 + t0) * 1024 + seg * 8;
    const unsigned short* gB1 = gB0 + 1024;
    unsigned short* lA0 = At + w * 512;
    unsigned short* lA1 = At + 2048 + w * 512;
    unsigned short* lB0 = Bt + w * 512;
    unsigned short* lB1 = Bt + 2048 + w * 512;

    f32x4 acc[4][4];
#pragma unroll
    for (int mi = 0; mi < 4; ++mi)
#pragma unroll
        for (int nj = 0; nj < 4; ++nj)
            acc[mi][nj] = f32x4{0.f, 0.f, 0.f, 0.f};

    for (int kk = 0; kk < 32; ++kk) {
        __syncthreads();
        gld_lds16(gA0, lA0);
        gld_lds16(gA1, lA1);
        gld_lds16(gB0, lB0);
        gld_lds16(gB1, lB1);
        gA0 += 32; gA1 += 32; gB0 += 32; gB1 += 32;
        __syncthreads();
        short8 af[4], bfr[4];
#pragma unroll
        for (int mi = 0; mi < 4; ++mi)
            af[mi] = *(const short8*)(At + (wm * 64 + mi * 16 + l15) * 32 + lq * 8);
#pragma unroll
        for (int nj = 0; nj < 4; ++nj)
            bfr[nj] = *(const short8*)(Bt + (wn * 64 + nj * 16 + l15) * 32 + lq * 8);
#pragma unroll
        for (int mi = 0; mi < 4; ++mi)
#pragma unroll
            for (int nj = 0; nj < 4; ++nj)
                acc[mi][nj] = __builtin_amdgcn_mfma_f32_16x16x32_bf16(af[mi], bfr[nj], acc[mi][nj], 0, 0, 0);
    }

    // epilogue: col c = wn*64 + nj*16 + l15 -> t = t0+wn, jb = nj, b16 = l15
#pragma unroll
    for (int mi = 0; mi < 4; ++mi) {
#pragma unroll
        for (int rr = 0; rr < 4; ++rr) {
            int np = n0 + wm * 64 + mi * 16 + lq * 4 + rr;
            float bs = bias[np];
#pragma unroll
            for (int nj = 0; nj < 4; ++nj) {
                size_t idx = ((((size_t)(t0 + wn)) * 4 + nj) * 4096 + np) * 16 + l15;
                Xg[idx] = f2bf(acc[mi][nj][rr] + bs);
            }
        }
    }
}

// --- phase 2: persistent recurrence (R11: 2-group interleave, R9 exchange).
// 64 blocks x 512 thr: pair=blk&1 -> jbA=2*pair, jbB=2*pair+1; ibb=blk>>1
// (n' rows [ibb*128,+128) = 32 hids x 4 gates). Wave w: rows ibb*128+w*16+
// [0,16). Lane (lq,l15): acc[rr] = gate-rr preact for hid=ibb*32+w*4+lq,
// batch=jb*16+l15. hbuf = 4 x bf16[64][1024] (BUFU64 u64 each); buf[t&3]
// holds h(t) for BOTH groups (disjoint row ranges).
__global__ __launch_bounds__(512, 1) void k_rec(const unsigned short* __restrict__ Wh,
                                                const unsigned short* __restrict__ Xg,
                                                const float* __restrict__ c0,
                                                unsigned short* __restrict__ hbuf) {
    const int blk  = blockIdx.x;
    const int pair = blk & 1;
    const int jbA  = pair * 2;
    const int jbB  = pair * 2 + 1;
    const int ibb  = blk >> 1;
    const int tid  = threadIdx.x;
    const int w    = tid >> 6;
    const int l    = tid & 63;
    const int l15  = l & 15, lq = l >> 4;

    __shared__ unsigned short hTlA[16 * 1032];   // [b16][k=1024], stride 1032
    __shared__ unsigned short hTlB[16 * 1032];
    __shared__ unsigned short hTr[16 * 36];      // h transpose scratch, pad 36

    // Persistent A-fragments: rows n' = ibb*128 + w*16 + l15, all K.
    // (R3 evidence: pinned frags land in AGPRs; MFMA reads AGPR A-ops free.)
    // Shared by both batch groups (weights are batch-independent).
    short8 afrag[32];
    {
        const unsigned short* wrow = Wh + (size_t)(ibb * 128 + w * 16 + l15) * 1024;
#pragma unroll
        for (int ks = 0; ks < 32; ++ks)
            afrag[ks] = *(const short8*)(wrow + ks * 32 + lq * 8);
#pragma unroll
        for (int ks = 0; ks < 32; ++ks)
            asm volatile("" : "+v"(afrag[ks]));
    }

    const int hid = ibb * 32 + w * 4 + lq;      // this lane's hidden unit
    float cA = c0[hid];
    float cB = cA;

    unsigned long long* hb64 = (unsigned long long*)hbuf;   // BUFU64 u64 / buf

    // stage mapping: thread -> (batch row sb, u64 lane sln)
    const int sb = tid >> 5, sln = tid & 31;
    const size_t prowA = (size_t)(jbA * 16 + sb) * 256;
    const size_t prowB = (size_t)(jbB * 16 + sb) * 256;

    // store/poison mapping (tid<128): 16 rows x 8 u64; 8 adjacent threads
    // cover one full 64B line (R10 lesson: never fragment a line).
    const int srow = tid >> 3, sseg = tid & 7;
    const size_t sidxA = (size_t)(jbA * 16 + srow) * 256 + ibb * 8 + sseg;
    const size_t sidxB = (size_t)(jbB * 16 + srow) * 256 + ibb * 8 + sseg;

    // Xg fixed part: (( (t*4+jb)*4096 + ibb*128 + w*16 + lq*4 + rr )*16 + l15
    const size_t xg_fix = ((size_t)ibb * 128 + w * 16 + lq * 4) * 16 + l15;

    float xgA[4], xgB[4];
#pragma unroll
    for (int rr = 0; rr < 4; ++rr)
        xgA[rr] = bf2f(Xg[((size_t)jbA * 4096 + rr) * 16 + xg_fix]);   // t = 0
#pragma unroll
    for (int rr = 0; rr < 4; ++rr)
        xgB[rr] = bf2f(Xg[((size_t)jbB * 4096 + rr) * 16 + xg_fix]);   // t = 0

    // prologue: stage h_A(0) from buf0 (k_misc-initialized; never poison)
    {
        const unsigned long long* src = hb64 + prowA;
        unsigned long long tmp[8];
#pragma unroll
        for (int p = 0; p < 8; ++p)
            tmp[p] = __hip_atomic_load(src + p * 32 + sln, __ATOMIC_RELAXED,
                                       __HIP_MEMORY_SCOPE_AGENT);
#pragma unroll
        for (int p = 0; p < 8; ++p)
            *(unsigned long long*)(&hTlA[sb * 1032 + (p * 32 + sln) * 4]) = tmp[p];
    }
    __syncthreads();

    for (int t = 0; t < SEQL; ++t) {
        // --- ph0: early-issue poll loads for h_B(t); latency hides under
        //     MFMA-A. If the compiler sinks them to ph4, behavior degrades
        //     to R9-style exposed poll (correct either way). ---
        const unsigned long long* srcB = hb64 + (size_t)(t & 3) * BUFU64 + prowB;
        unsigned long long tmpB[8];
#pragma unroll
        for (int p = 0; p < 8; ++p)
            tmpB[p] = __hip_atomic_load(srcB + p * 32 + sln, __ATOMIC_RELAXED,
                                        __HIP_MEMORY_SCOPE_AGENT);

        // --- ph1: MFMA-A over K=1024 (two chains, R9 order) + gates-A ---
        {
            f32x4 acc0 = {0.f, 0.f, 0.f, 0.f}, acc1 = {0.f, 0.f, 0.f, 0.f};
#pragma unroll
            for (int ks = 0; ks < 32; ks += 2) {
                short8 b0 = *(const short8*)(&hTlA[l15 * 1032 + ks * 32 + lq * 8]);
                short8 b1 = *(const short8*)(&hTlA[l15 * 1032 + (ks + 1) * 32 + lq * 8]);
                acc0 = __builtin_amdgcn_mfma_f32_16x16x32_bf16(afrag[ks], b0, acc0, 0, 0, 0);
                acc1 = __builtin_amdgcn_mfma_f32_16x16x32_bf16(afrag[ks + 1], b1, acc1, 0, 0, 0);
            }
            float pi = acc0[0] + acc1[0] + xgA[0];
            float pf = acc0[1] + acc1[1] + xgA[1];
            float po = acc0[2] + acc1[2] + xgA[2];
            float pg = acc0[3] + acc1[3] + xgA[3];
            float ig = sigmoidf_fast(pi);
            float fg = sigmoidf_fast(pf);
            float og = sigmoidf_fast(po);
            float gg = tanhf_fast(pg);
            cA = fg * cA + ig * gg;
            float hh = og * tanhf_fast(cA);
            hTr[l15 * 36 + w * 4 + lq] = f2bf(hh);
        }
        __syncthreads();   // ph2: hTr-A ready; hTlA fully consumed

        // --- ph3: store h_A(t+1) + poison A's retired buf[(t-1)&3] ---
        if (tid < 128) {
            unsigned long long v = *(const unsigned long long*)(&hTr[srow * 36 + sseg * 4]);
            asm volatile("s_waitcnt vmcnt(0)" ::: "memory");   // drain prior poison
            __hip_atomic_store(hb64 + (size_t)((t + 1) & 3) * BUFU64 + sidxA, v,
                               __ATOMIC_RELAXED, __HIP_MEMORY_SCOPE_AGENT);
            __hip_atomic_store(hb64 + (size_t)((t + 3) & 3) * BUFU64 + sidxA, POISON,
                               __ATOMIC_RELAXED, __HIP_MEMORY_SCOPE_AGENT);
        }

        // --- ph4: check tmpB (retry on poison), stage into hTlB ---
        {
            for (;;) {
                int miss = 0;
#pragma unroll
                for (int p = 0; p < 8; ++p)
                    if (tmpB[p] == POISON) miss |= 1 << p;
                if (!miss) break;
                __builtin_amdgcn_s_sleep(1);
#pragma unroll
                for (int p = 0; p < 8; ++p)
                    if (miss & (1 << p))
                        tmpB[p] = __hip_atomic_load(srcB + p * 32 + sln,
                                                    __ATOMIC_RELAXED,
                                                    __HIP_MEMORY_SCOPE_AGENT);
            }
#pragma unroll
            for (int p = 0; p < 8; ++p)
                *(unsigned long long*)(&hTlB[sb * 1032 + (p * 32 + sln) * 4]) = tmpB[p];
        }
        __syncthreads();   // ph5: hTlB ready; hTr-A store-reads done

        // --- ph6: MFMA-B + gates-B ---
        {
            f32x4 acc0 = {0.f, 0.f, 0.f, 0.f}, acc1 = {0.f, 0.f, 0.f, 0.f};
#pragma unroll
            for (int ks = 0; ks < 32; ks += 2) {
                short8 b0 = *(const short8*)(&hTlB[l15 * 1032 + ks * 32 + lq * 8]);
                short8 b1 = *(const short8*)(&hTlB[l15 * 1032 + (ks + 1) * 32 + lq * 8]);
                acc0 = __builtin_amdgcn_mfma_f32_16x16x32_bf16(afrag[ks], b0, acc0, 0, 0, 0);
                acc1 = __builtin_amdgcn_mfma_f32_16x16x32_bf16(afrag[ks + 1], b1, acc1, 0, 0, 0);
            }
            float pi = acc0[0] + acc1[0] + xgB[0];
            float pf = acc0[1] + acc1[1] + xgB[1];
            float po = acc0[2] + acc1[2] + xgB[2];
            float pg = acc0[3] + acc1[3] + xgB[3];
            float ig = sigmoidf_fast(pi);
            float fg = sigmoidf_fast(pf);
            float og = sigmoidf_fast(po);
            float gg = tanhf_fast(pg);
            cB = fg * cB + ig * gg;
            float hh = og * tanhf_fast(cB);
            hTr[l15 * 36 + w * 4 + lq] = f2bf(hh);
        }
        __syncthreads();   // ph7: hTr-B ready

        // --- ph8: store h_B(t+1) + poison B's retired buf[(t-1)&3] ---
        if (tid < 128) {
            unsigned long long v = *(const unsigned long long*)(&hTr[srow * 36 + sseg * 4]);
            asm volatile("s_waitcnt vmcnt(0)" ::: "memory");
            __hip_atomic_store(hb64 + (size_t)((t + 1) & 3) * BUFU64 + sidxB, v,
                               __ATOMIC_RELAXED, __HIP_MEMORY_SCOPE_AGENT);
            __hip_atomic_store(hb64 + (size_t)((t + 3) & 3) * BUFU64 + sidxB, POISON,
                               __ATOMIC_RELAXED, __HIP_MEMORY_SCOPE_AGENT);
        }

        // --- ph9: poll+stage h_A(t+1) (slack: MFMA-B elapsed since pair-
        //     blocks' ph3 stores); Xg prefetch for t+1 ---
        if (t < SEQL - 1) {
            const unsigned long long* srcA =
                hb64 + (size_t)((t + 1) & 3) * BUFU64 + prowA;
            unsigned long long tmpA[8];
#pragma unroll
            for (int p = 0; p < 8; ++p)
                tmpA[p] = __hip_atomic_load(srcA + p * 32 + sln, __ATOMIC_RELAXED,
                                            __HIP_MEMORY_SCOPE_AGENT);
            for (;;) {
                int miss = 0;
#pragma unroll
                for (int p = 0; p < 8; ++p)
                    if (tmpA[p] == POISON) miss |= 1 << p;
                if (!miss) break;
                __builtin_amdgcn_s_sleep(1);
#pragma unroll
                for (int p = 0; p < 8; ++p)
                    if (miss & (1 << p))
                        tmpA[p] = __hip_atomic_load(srcA + p * 32 + sln,
                                                    __ATOMIC_RELAXED,
                                                    __HIP_MEMORY_SCOPE_AGENT);
            }
#pragma unroll
            for (int p = 0; p < 8; ++p)
                *(unsigned long long*)(&hTlA[sb * 1032 + (p * 32 + sln) * 4]) = tmpA[p];

            size_t baseA = (((size_t)(t + 1) * 4 + jbA) * 4096) * 16 + xg_fix;
            size_t baseB = (((size_t)(t + 1) * 4 + jbB) * 4096) * 16 + xg_fix;
#pragma unroll
            for (int rr = 0; rr < 4; ++rr)
                xgA[rr] = bf2f(Xg[baseA + (size_t)rr * 16]);
#pragma unroll
            for (int rr = 0; rr < 4; ++rr)
                xgB[rr] = bf2f(Xg[baseB + (size_t)rr * 16]);
        }
        __syncthreads();   // ph10: hTlA ready for next ph1; hTr reusable
    }
    // t=511 stores h(512) into buf[512&3] = buf0: final h at hbuf base
}

// --- output: out[b][o] = sum_k h[b][k] * w[o][k]
__global__ __launch_bounds__(256) void k_out(const unsigned short* __restrict__ hT,
                                             const float* __restrict__ wT,
                                             float* __restrict__ out) {
    const int b = blockIdx.x;
    const int tid = threadIdx.x;
    __shared__ float hs[1024];
#pragma unroll
    for (int p = 0; p < 4; ++p)
        hs[p * 256 + tid] = bf2f(hT[b * 1024 + p * 256 + tid]);
    __syncthreads();
    float a0 = 0.f, a1 = 0.f;
    for (int k = 0; k < 1024; ++k) {
        float hv = hs[k];
        a0 = fmaf(hv, wT[k * 512 + tid], a0);
        a1 = fmaf(hv, wT[k * 512 + 256 + tid], a1);
    }
    out[b * 512 + tid] = a0;
    out[b * 512 + 256 + tid] = a1;
}

extern "C" void kernel_launch(void* const* d_in, const int* in_sizes, int n_in,
                              void* d_out, int out_size, void* d_ws, size_t ws_size,
                              hipStream_t stream) {
    const float* X    = (const float*)d_in[0];
    const float* c0   = (const float*)d_in[1];
    const float* h0   = (const float*)d_in[2];
    const float* w_hi = (const float*)d_in[3];
    const float* w_xi = (const float*)d_in[4];
    const float* b_hi = (const float*)d_in[5];
    const float* b_xi = (const float*)d_in[6];
    const float* w_hf = (const float*)d_in[7];
    const float* w_xf = (const float*)d_in[8];
    const float* b_hf = (const float*)d_in[9];
    const float* b_xf = (const float*)d_in[10];
    const float* w_ho = (const float*)d_in[11];
    const float* w_xo = (const float*)d_in[12];
    const float* b_ho = (const float*)d_in[13];
    const float* b_xo = (const float*)d_in[14];
    const float* w_hg = (const float*)d_in[15];
    const float* w_xg = (const float*)d_in[16];
    const float* b_hg = (const float*)d_in[17];
    const float* b_xg = (const float*)d_in[18];
    const float* w    = (const float*)d_in[19];

    // workspace layout (16B aligned); ~339 MiB
    char* ws = (char*)d_ws;
    size_t off = 0;
    unsigned short* Xg  = (unsigned short*)(ws + off); off += (size_t)512 * 4096 * 64 * 2;
    unsigned short* Whp = (unsigned short*)(ws + off); off += (size_t)4096 * 1024 * 2;
    unsigned short* Wxp = (unsigned short*)(ws + off); off += (size_t)4096 * 1024 * 2;
    unsigned short* Xb  = (unsigned short*)(ws + off); off += (size_t)64 * 512 * 1024 * 2;
    float*          bias= (float*)(ws + off);          off += (size_t)4096 * 4;
    float*          wT  = (float*)(ws + off);          off += (size_t)1024 * 512 * 4;
    unsigned short* hbuf= (unsigned short*)(ws + off); off += (size_t)4 * 64 * 1024 * 2;
    if (ws_size < off) return;

    k_pack_w<<<4096, 256, 0, stream>>>(w_hi, w_hf, w_ho, w_hg, Whp);
    k_pack_w<<<4096, 256, 0, stream>>>(w_xi, w_xf, w_xo, w_xg, Wxp);
    k_misc<<<(4096 + 65536 + 524288 + 3 * BUFU64 + 255) / 256, 256, 0, stream>>>(
        b_hi, b_xi, b_hf, b_xf, b_ho, b_xo, b_hg, b_xg, h0, w, bias, hbuf, wT);
    k_convert_x<<<33554432 / 4 / 256, 256, 0, stream>>>(X, Xb);

    k_xgemm<<<dim3(256, 32), 256, 0, stream>>>(Wxp, Xb, bias, Xg);

    void* args[] = {(void*)&Whp, (void*)&Xg, (void*)&c0, (void*)&hbuf};
    hipLaunchCooperativeKernel((void*)k_rec, dim3(64), dim3(512), args, 0, stream);

    k_out<<<64, 256, 0, stream>>>(hbuf, wT, (float*)d_out);
}

// Round 7
// 1819.797 us; speedup vs baseline: 2.3551x; 1.7759x over previous
//
#include <hip/hip_runtime.h>

// ---------------------------------------------------------------------------
// LSTM: B=64, SEQ=512, I=1024, H=1024, O=512, fp32 in/out.
// Row space: n' = hid*4 + gate (gate-interleaved) so MFMA C-layout puts all
// 4 gate preacts of one (hid,batch) in ONE lane (acc[rr] = gate rr).
//   prep: pack Wh4/Wx4 -> bf16 [n'=4096][1024], bias[n'], X->bf16,
//         h0 chunk-layout buffer + poison bufs 1..3, wT for output GEMM
//   R13:  R12 logic inside PROVEN resource envelopes. R12 failed with
//         absmax ~= max|ref| (h never updated -> zeros): launch-failure
//         signature, not data corruption. R12 was the first 256-block
//         cooperative launch at exact capacity AND 99.7KB LDS (proven max:
//         67.5KB, R11). R13: (1) single xTl buffer -> LDS 66.7KB; x(t+1)
//         prefetch issued after barrier-3 of step t (barrier-3 separates
//         it from slack(t-1) readers even under wave skew; barrier-6
//         drains before slack(t) reads). (2) PLAIN launch, grid=256 x 256
//         thr, 1 block/CU: all blocks resident structurally -> spin-poll
//         safe; removes cooperative at-capacity validation. (3) afragX
//         unpinned (only afragH keeps the R3-proven pin).
//         Fusion design (R12): block owns 64 n' rows; Wh+Wx frags in regs;
//         xg(t+1) = Wx.x(t+1)+bias computed by MFMA in the wait window
//         between h-store and next poll. k_xgemm deleted; Xg traffic gone.
//         Exchange = R9's poison data-poll, 4 rotating buffers; h chunks
//         [jb][ibb][b16][hid16] so the 64-thr store = 4 full 128B lines.
//   out:  out[b][o] = h[b,:] . w[o,:]  (chunk-layout translated)
// ---------------------------------------------------------------------------

typedef short short8 __attribute__((ext_vector_type(8)));   // 8 bf16
typedef float f32x4 __attribute__((ext_vector_type(4)));

typedef __attribute__((address_space(1))) const unsigned int glb_u32;
typedef __attribute__((address_space(3))) unsigned int lds_u32;

#define SEQL  512
#define POISON 0xFFFFFFFFFFFFFFFFull
#define BUFU64 16384     // u64 per h buffer: 4 groups x 64 chunks x 64 u64

__device__ __forceinline__ unsigned short f2bf(float f) {
    unsigned int u = __builtin_bit_cast(unsigned int, f);
    u += 0x7FFFu + ((u >> 16) & 1u);            // round-to-nearest-even
    return (unsigned short)(u >> 16);
}
__device__ __forceinline__ float bf2f(unsigned short s) {
    unsigned int u = ((unsigned int)s) << 16;
    return __builtin_bit_cast(float, u);
}
__device__ __forceinline__ float sigmoidf_fast(float x) {
    return 1.f / (1.f + __expf(-x));
}
__device__ __forceinline__ float tanhf_fast(float x) {
    return 1.f - 2.f / (1.f + __expf(2.f * x));
}
__device__ __forceinline__ void gld_lds16(const unsigned short* g, unsigned short* l) {
    __builtin_amdgcn_global_load_lds((glb_u32*)g, (lds_u32*)l, 16, 0, 0);
}

// --- prep: pack 4 gate weight mats (fp32 [1024][1024]) into bf16 [n'][1024]
__global__ void k_pack_w(const float* __restrict__ w0, const float* __restrict__ w1,
                         const float* __restrict__ w2, const float* __restrict__ w3,
                         unsigned short* __restrict__ dst) {
    int idx4 = blockIdx.x * blockDim.x + threadIdx.x;   // over 4096*256
    int np = idx4 >> 8;            // n' 0..4095
    int k4 = (idx4 & 255) * 4;
    int g = np & 3, r = np >> 2;
    const float* src = (g == 0) ? w0 : (g == 1) ? w1 : (g == 2) ? w2 : w3;
    float4 v = *(const float4*)(src + r * 1024 + k4);
    ushort4 o;
    o.x = f2bf(v.x); o.y = f2bf(v.y); o.z = f2bf(v.z); o.w = f2bf(v.w);
    *(ushort4*)(dst + (size_t)np * 1024 + k4) = o;
}

// --- prep: bias[n'], h0 -> buf0 chunk layout, poison bufs 1..3, wT
__global__ void k_misc(const float* __restrict__ b_hi, const float* __restrict__ b_xi,
                       const float* __restrict__ b_hf, const float* __restrict__ b_xf,
                       const float* __restrict__ b_ho, const float* __restrict__ b_xo,
                       const float* __restrict__ b_hg, const float* __restrict__ b_xg,
                       const float* __restrict__ h0, const float* __restrict__ w,
                       float* __restrict__ bias, unsigned short* __restrict__ hbuf,
                       float* __restrict__ wT) {
    int idx = blockIdx.x * blockDim.x + threadIdx.x;
    if (idx < 4096) {
        int g = idx & 3, r = idx >> 2;                  // n'-order bias
        const float* bh = (g == 0) ? b_hi : (g == 1) ? b_hf : (g == 2) ? b_ho : b_hg;
        const float* bx = (g == 0) ? b_xi : (g == 1) ? b_xf : (g == 2) ? b_xo : b_xg;
        bias[idx] = bh[r] + bx[r];
    } else if (idx < 4096 + 65536) {
        int e = idx - 4096;              // buf0 short idx: [cg][b16][hid16]
        int cg = e >> 8;                 // jb*64 + ibb
        int h16 = e & 15;
        hbuf[e] = f2bf(h0[(cg & 63) * 16 + h16]);   // hid = ibb*16 + h16
    } else if (idx < 4096 + 65536 + 524288) {
        int e = idx - 69632;
        int k = e >> 9, o = e & 511;
        wT[e] = w[o * 1024 + k];
    } else if (idx < 4096 + 65536 + 524288 + 3 * BUFU64) {
        int e = idx - (4096 + 65536 + 524288);          // poison bufs 1..3
        ((unsigned long long*)hbuf)[BUFU64 + e] = POISON;
    }
}

// --- prep: X fp32 -> bf16 (layout [b][t][k] preserved)
__global__ void k_convert_x(const float* __restrict__ X, unsigned short* __restrict__ Xb) {
    int idx = blockIdx.x * blockDim.x + threadIdx.x;
    float4 v = ((const float4*)X)[idx];
    ushort4 o;
    o.x = f2bf(v.x); o.y = f2bf(v.y); o.z = f2bf(v.z); o.w = f2bf(v.w);
    ((ushort4*)Xb)[idx] = o;
}

// --- fused persistent recurrence (R13).
// 256 blocks x 256 thr: jb=blk&3 (16 batches), ibb=blk>>2 (0..63): n' rows
// [ibb*64,+64) = 16 hids x 4 gates. Wave w (0..3): rows ibb*64+w*16+[0,16).
// Lane (lq,l15): acc[rr] = gate-rr preact for hid=ibb*16+w*4+lq, b=jb*16+l15.
// h chunk (512B) = u64[(jb*64+ibb)*64 + b16*4 + l4] holding hids l4*4..+4.
__global__ __launch_bounds__(256, 1) void k_rec(const unsigned short* __restrict__ Wh,
                                                const unsigned short* __restrict__ Wx,
                                                const unsigned short* __restrict__ Xb,
                                                const float* __restrict__ bias,
                                                const float* __restrict__ c0,
                                                unsigned short* __restrict__ hbuf) {
    const int blk = blockIdx.x;
    const int jb  = blk & 3;
    const int ibb = blk >> 2;
    const int tid = threadIdx.x;
    const int w   = tid >> 6;
    const int l   = tid & 63;
    const int l15 = l & 15, lq = l >> 4;

    __shared__ unsigned short hTl[16 * 1032];   // h(t) tile [b16][k=1024]
    __shared__ unsigned short xTl[16 * 1032];   // x tile (single buffer)
    __shared__ unsigned short hTr[16 * 20];     // h out [b16][hid16], pad 20

    // Persistent A-fragments for BOTH GEMMs: rows n' = ibb*64 + w*16 + l15.
    // afragH pinned (R3 evidence); afragX left to the allocator.
    short8 afragH[32], afragX[32];
    {
        const unsigned short* wrH = Wh + (size_t)(ibb * 64 + w * 16 + l15) * 1024;
        const unsigned short* wrX = Wx + (size_t)(ibb * 64 + w * 16 + l15) * 1024;
#pragma unroll
        for (int ks = 0; ks < 32; ++ks)
            afragH[ks] = *(const short8*)(wrH + ks * 32 + lq * 8);
#pragma unroll
        for (int ks = 0; ks < 32; ++ks)
            afragX[ks] = *(const short8*)(wrX + ks * 32 + lq * 8);
#pragma unroll
        for (int ks = 0; ks < 32; ++ks)
            asm volatile("" : "+v"(afragH[ks]));
    }

    const int hid = ibb * 16 + w * 4 + lq;
    float c = c0[hid];
    float bias4[4];
#pragma unroll
    for (int rr = 0; rr < 4; ++rr)
        bias4[rr] = bias[(size_t)ibb * 64 + w * 16 + lq * 4 + rr];

    unsigned long long* hb64 = (unsigned long long*)hbuf;

    // stage mapping: thread tid handles u64s g = p*256+tid, p=0..15;
    // decode: chunk ibb_src = p*4+w, batch b16 = (tid>>2)&15, l4 = tid&3;
    // LDS k = ibb_src*16 + l4*4 = p*64 + w*16 + l4*4.
    const int sbb = (tid >> 2) & 15, sl4 = tid & 3;
    const int stage_sh = sbb * 1032 + w * 16 + sl4 * 4;   // + p*64 shorts

    // prologue: stage x(0) -> xTl, compute xg(0)
#pragma unroll
    for (int i = 0; i < 8; ++i) {
        int r = w * 8 + i, b16 = r >> 1, half = r & 1;
        const unsigned short* src =
            Xb + ((size_t)(jb * 16 + b16) * 512 + 0) * 1024 + half * 512 + l * 8;
        gld_lds16(src, &xTl[b16 * 1032 + half * 512]);
    }
    asm volatile("s_waitcnt vmcnt(0)" ::: "memory");
    __syncthreads();

    float xg[4];
    {
        f32x4 xa0 = {0.f, 0.f, 0.f, 0.f}, xa1 = {0.f, 0.f, 0.f, 0.f};
#pragma unroll
        for (int ks = 0; ks < 32; ks += 2) {
            short8 b0 = *(const short8*)(&xTl[l15 * 1032 + ks * 32 + lq * 8]);
            short8 b1 = *(const short8*)(&xTl[l15 * 1032 + (ks + 1) * 32 + lq * 8]);
            xa0 = __builtin_amdgcn_mfma_f32_16x16x32_bf16(afragX[ks], b0, xa0, 0, 0, 0);
            xa1 = __builtin_amdgcn_mfma_f32_16x16x32_bf16(afragX[ks + 1], b1, xa1, 0, 0, 0);
        }
#pragma unroll
        for (int rr = 0; rr < 4; ++rr)
            xg[rr] = xa0[rr] + xa1[rr] + bias4[rr];
    }

    for (int t = 0; t < SEQL; ++t) {
        // --- poll + stage h(t) (data arrival IS the flag) ---
        {
            const unsigned long long* src =
                hb64 + (size_t)(t & 3) * BUFU64 + (size_t)jb * 4096 + tid;
            unsigned long long tmp[16];
#pragma unroll
            for (int p = 0; p < 16; ++p)
                tmp[p] = __hip_atomic_load(src + p * 256, __ATOMIC_RELAXED,
                                           __HIP_MEMORY_SCOPE_AGENT);
            for (;;) {
                unsigned miss = 0;
#pragma unroll
                for (int p = 0; p < 16; ++p)
                    if (tmp[p] == POISON) miss |= 1u << p;
                if (!miss) break;
                __builtin_amdgcn_s_sleep(1);
#pragma unroll
                for (int p = 0; p < 16; ++p)
                    if (miss & (1u << p))
                        tmp[p] = __hip_atomic_load(src + p * 256, __ATOMIC_RELAXED,
                                                   __HIP_MEMORY_SCOPE_AGENT);
            }
#pragma unroll
            for (int p = 0; p < 16; ++p)
                *(unsigned long long*)(&hTl[stage_sh + p * 64]) = tmp[p];
        }
        __syncthreads();   // (3) hTl complete; all waves past slack(t-1)

        // --- prefetch x(t+1) -> xTl (single buffer; barrier-3 separated it
        //     from slack(t-1) readers; barrier-6 drains before slack(t)) ---
        if (t < SEQL - 1) {
#pragma unroll
            for (int i = 0; i < 8; ++i) {
                int r = w * 8 + i, b16 = r >> 1, half = r & 1;
                const unsigned short* src =
                    Xb + ((size_t)(jb * 16 + b16) * 512 + (t + 1)) * 1024 + half * 512 + l * 8;
                gld_lds16(src, &xTl[b16 * 1032 + half * 512]);
            }
        }

        // --- MFMA-h (R9 chain order) + gates ---
        {
            f32x4 a0 = {0.f, 0.f, 0.f, 0.f}, a1 = {0.f, 0.f, 0.f, 0.f};
#pragma unroll
            for (int ks = 0; ks < 32; ks += 2) {
                short8 b0 = *(const short8*)(&hTl[l15 * 1032 + ks * 32 + lq * 8]);
                short8 b1 = *(const short8*)(&hTl[l15 * 1032 + (ks + 1) * 32 + lq * 8]);
                a0 = __builtin_amdgcn_mfma_f32_16x16x32_bf16(afragH[ks], b0, a0, 0, 0, 0);
                a1 = __builtin_amdgcn_mfma_f32_16x16x32_bf16(afragH[ks + 1], b1, a1, 0, 0, 0);
            }
            float pi = a0[0] + a1[0] + xg[0];
            float pf = a0[1] + a1[1] + xg[1];
            float po = a0[2] + a1[2] + xg[2];
            float pg = a0[3] + a1[3] + xg[3];
            float ig = sigmoidf_fast(pi);
            float fg = sigmoidf_fast(pf);
            float og = sigmoidf_fast(po);
            float gg = tanhf_fast(pg);
            c = fg * c + ig * gg;
            float hh = og * tanhf_fast(c);
            hTr[l15 * 20 + w * 4 + lq] = f2bf(hh);
        }
        __syncthreads();   // (6) hTr ready; hTl reads done; xTl drained

        // --- store h(t+1) chunk (64 thr x 8B = 4 full 128B lines) + poison
        //     retired buf[(t-1)&3]. vmcnt(0) drains prior poison first. ---
        if (tid < 64) {
            int b = tid >> 2, l4 = tid & 3;
            unsigned long long v = *(const unsigned long long*)(&hTr[b * 20 + l4 * 4]);
            asm volatile("s_waitcnt vmcnt(0)" ::: "memory");
            size_t u = (size_t)(jb * 64 + ibb) * 64 + b * 4 + l4;
            __hip_atomic_store(hb64 + (size_t)((t + 1) & 3) * BUFU64 + u, v,
                               __ATOMIC_RELAXED, __HIP_MEMORY_SCOPE_AGENT);
            __hip_atomic_store(hb64 + (size_t)((t + 3) & 3) * BUFU64 + u, POISON,
                               __ATOMIC_RELAXED, __HIP_MEMORY_SCOPE_AGENT);
        }

        // --- SLACK FILL: xg(t+1) via MFMA-x while h(t+1) commits ---
        if (t < SEQL - 1) {
            f32x4 xa0 = {0.f, 0.f, 0.f, 0.f}, xa1 = {0.f, 0.f, 0.f, 0.f};
#pragma unroll
            for (int ks = 0; ks < 32; ks += 2) {
                short8 b0 = *(const short8*)(&xTl[l15 * 1032 + ks * 32 + lq * 8]);
                short8 b1 = *(const short8*)(&xTl[l15 * 1032 + (ks + 1) * 32 + lq * 8]);
                xa0 = __builtin_amdgcn_mfma_f32_16x16x32_bf16(afragX[ks], b0, xa0, 0, 0, 0);
                xa1 = __builtin_amdgcn_mfma_f32_16x16x32_bf16(afragX[ks + 1], b1, xa1, 0, 0, 0);
            }
#pragma unroll
            for (int rr = 0; rr < 4; ++rr)
                xg[rr] = xa0[rr] + xa1[rr] + bias4[rr];
        }
    }
    // t=511 stores h(512) into buf[512&3] = buf0: final h at hbuf base
}

// --- output: out[b][o] = sum_k h[b][k] * w[o][k]  (chunk-layout source)
__global__ __launch_bounds__(256) void k_out(const unsigned short* __restrict__ hT,
                                             const float* __restrict__ wT,
                                             float* __restrict__ out) {
    const int b = blockIdx.x;
    const int jb = b >> 4, b16 = b & 15;
    const int tid = threadIdx.x;
    __shared__ float hs[1024];
#pragma unroll
    for (int p = 0; p < 4; ++p) {
        int k = p * 256 + tid;
        hs[k] = bf2f(hT[(size_t)(jb * 64 + (k >> 4)) * 256 + b16 * 16 + (k & 15)]);
    }
    __syncthreads();
    float a0 = 0.f, a1 = 0.f;
    for (int k = 0; k < 1024; ++k) {
        float hv = hs[k];
        a0 = fmaf(hv, wT[k * 512 + tid], a0);
        a1 = fmaf(hv, wT[k * 512 + 256 + tid], a1);
    }
    out[b * 512 + tid] = a0;
    out[b * 512 + 256 + tid] = a1;
}

extern "C" void kernel_launch(void* const* d_in, const int* in_sizes, int n_in,
                              void* d_out, int out_size, void* d_ws, size_t ws_size,
                              hipStream_t stream) {
    const float* X    = (const float*)d_in[0];
    const float* c0   = (const float*)d_in[1];
    const float* h0   = (const float*)d_in[2];
    const float* w_hi = (const float*)d_in[3];
    const float* w_xi = (const float*)d_in[4];
    const float* b_hi = (const float*)d_in[5];
    const float* b_xi = (const float*)d_in[6];
    const float* w_hf = (const float*)d_in[7];
    const float* w_xf = (const float*)d_in[8];
    const float* b_hf = (const float*)d_in[9];
    const float* b_xf = (const float*)d_in[10];
    const float* w_ho = (const float*)d_in[11];
    const float* w_xo = (const float*)d_in[12];
    const float* b_ho = (const float*)d_in[13];
    const float* b_xo = (const float*)d_in[14];
    const float* w_hg = (const float*)d_in[15];
    const float* w_xg = (const float*)d_in[16];
    const float* b_hg = (const float*)d_in[17];
    const float* b_xg = (const float*)d_in[18];
    const float* w    = (const float*)d_in[19];

    // workspace layout (16B aligned); ~83 MiB
    char* ws = (char*)d_ws;
    size_t off = 0;
    unsigned short* Whp = (unsigned short*)(ws + off); off += (size_t)4096 * 1024 * 2;
    unsigned short* Wxp = (unsigned short*)(ws + off); off += (size_t)4096 * 1024 * 2;
    unsigned short* Xb  = (unsigned short*)(ws + off); off += (size_t)64 * 512 * 1024 * 2;
    float*          bias= (float*)(ws + off);          off += (size_t)4096 * 4;
    float*          wT  = (float*)(ws + off);          off += (size_t)1024 * 512 * 4;
    unsigned short* hbuf= (unsigned short*)(ws + off); off += (size_t)4 * 64 * 1024 * 2;
    if (ws_size < off) return;

    k_pack_w<<<4096, 256, 0, stream>>>(w_hi, w_hf, w_ho, w_hg, Whp);
    k_pack_w<<<4096, 256, 0, stream>>>(w_xi, w_xf, w_xo, w_xg, Wxp);
    k_misc<<<(4096 + 65536 + 524288 + 3 * BUFU64 + 255) / 256, 256, 0, stream>>>(
        b_hi, b_xi, b_hf, b_xf, b_ho, b_xo, b_hg, b_xg, h0, w, bias, hbuf, wT);
    k_convert_x<<<33554432 / 4 / 256, 256, 0, stream>>>(X, Xb);

    // Plain launch: 256 blocks at 1 block/CU on 256 CUs -> all co-resident
    // structurally; removes cooperative at-capacity validation (R12 suspect).
    k_rec<<<dim3(256), dim3(256), 0, stream>>>(Whp, Wxp, Xb, bias, c0, hbuf);

    k_out<<<64, 256, 0, stream>>>(hbuf, wT, (float*)d_out);
}